// Round 2
// baseline (817.809 us; speedup 1.0000x reference)
//
#include <hip/hip_runtime.h>
#include <hip/hip_bf16.h>
#include <math.h>

// Problem constants (from reference setup_inputs)
#define B_  256
#define S_  20
#define V_  20000
#define C_  20
#define D_  64
#define MTOT (B_*S_ + B_)      // 5376 rows: 5120 support + 256 target
#define KSPLIT 10
#define KCHUNK (V_/KSPLIT)     // 2000
#define KC 80                  // K staged per LDS chunk
#define MT 64                  // rows per block
#define LDSW 84                // padded LDS row stride in dwords (80+4)

// ---------------------------------------------------------------------------
// Phase 1: E_partial[bk][m][d] = sum_{k in chunk bk} X[m][k] * W[d][k]
// X rows 0..5119 = support_set_images reshaped [5120,20000],
// rows 5120..5375 = target_image [256,20000]. Bias added in phase 2.
// Micro-tile: 256 thr, thread (tm=t>>4, td=t&15) owns m = m0+tm+16i,
// d = td+16j (i,j in 0..3) -> 16 fp32 accumulators.
// ---------------------------------------------------------------------------
__global__ __launch_bounds__(256)
void gemm_part_kernel(const float* __restrict__ sup,
                      const float* __restrict__ tgtim,
                      const float* __restrict__ W,
                      float* __restrict__ Ep) {
    __shared__ float Xs[MT * LDSW];
    __shared__ float Ws[D_ * LDSW];

    const int bm = blockIdx.x;          // 0..83
    const int bk = blockIdx.y;          // 0..KSPLIT-1
    const int t  = threadIdx.x;
    const int tm = t >> 4;              // 0..15
    const int td = t & 15;              // 0..15
    const int m0 = bm * MT;

    // A block is entirely support (bm<80) or entirely target (bm>=80).
    const float* xbase = (m0 < B_*S_)
        ? (sup   + (size_t)m0 * V_)
        : (tgtim + (size_t)(m0 - B_*S_) * V_);

    float acc[4][4];
#pragma unroll
    for (int i = 0; i < 4; ++i)
#pragma unroll
        for (int j = 0; j < 4; ++j) acc[i][j] = 0.f;

    const size_t kbase0 = (size_t)bk * KCHUNK;

    for (int ch = 0; ch < KCHUNK / KC; ++ch) {
        const size_t kb = kbase0 + (size_t)ch * KC;
        __syncthreads();
        // Stage X tile: 64 rows x 80 floats (1280 float4, 5 per thread)
#pragma unroll
        for (int u = t; u < (MT * KC) / 4; u += 256) {
            const int r = u / (KC / 4);
            const int c = u % (KC / 4);
            const float4 v = *(const float4*)(xbase + (size_t)r * V_ + kb + c * 4);
            *(float4*)&Xs[r * LDSW + c * 4] = v;
        }
        // Stage W tile: 64 rows x 80 floats
#pragma unroll
        for (int u = t; u < (D_ * KC) / 4; u += 256) {
            const int r = u / (KC / 4);
            const int c = u % (KC / 4);
            const float4 v = *(const float4*)(W + (size_t)r * V_ + kb + c * 4);
            *(float4*)&Ws[r * LDSW + c * 4] = v;
        }
        __syncthreads();

#pragma unroll
        for (int kq = 0; kq < KC; kq += 4) {
            float4 xf[4], wf[4];
#pragma unroll
            for (int i = 0; i < 4; ++i)
                xf[i] = *(const float4*)&Xs[(tm + 16 * i) * LDSW + kq];
#pragma unroll
            for (int j = 0; j < 4; ++j)
                wf[j] = *(const float4*)&Ws[(td + 16 * j) * LDSW + kq];
#pragma unroll
            for (int i = 0; i < 4; ++i)
#pragma unroll
                for (int j = 0; j < 4; ++j) {
                    acc[i][j] += xf[i].x * wf[j].x;
                    acc[i][j] += xf[i].y * wf[j].y;
                    acc[i][j] += xf[i].z * wf[j].z;
                    acc[i][j] += xf[i].w * wf[j].w;
                }
        }
    }

#pragma unroll
    for (int i = 0; i < 4; ++i)
#pragma unroll
        for (int j = 0; j < 4; ++j) {
            const size_t m = (size_t)m0 + tm + 16 * i;
            Ep[((size_t)bk * MTOT + m) * D_ + (td + 16 * j)] = acc[i][j];
        }
}

// ---------------------------------------------------------------------------
// Phase 2: per-sample distance + softmax + preds + argmax + CE loss.
// One 64-thread wave per batch element b; lane d owns feature d.
// ---------------------------------------------------------------------------
__global__ __launch_bounds__(64)
void phase2_kernel(const float* __restrict__ Ep,
                   const float* __restrict__ bias,
                   const float* __restrict__ onehot,
                   const int*   __restrict__ ty_,
                   float* __restrict__ res) {
    const int b = blockIdx.x;
    const int d = threadIdx.x;

    const float bv = bias[d];

    // Reduce K-split partials: sup[s][d] and tgt[d]
    float supv[S_];
#pragma unroll
    for (int s = 0; s < S_; ++s) {
        float v = 0.f;
#pragma unroll
        for (int p = 0; p < KSPLIT; ++p)
            v += Ep[((size_t)p * MTOT + b * S_ + s) * D_ + d];
        supv[s] = v + bv;
    }
    float tg = 0.f;
#pragma unroll
    for (int p = 0; p < KSPLIT; ++p)
        tg += Ep[((size_t)p * MTOT + B_ * S_ + b) * D_ + d];
    tg += bv;

    // similarities[s] = dot(tgt,sup_s) * rsqrt(clip(||sup_s||^2, 1e-10))
    float sims[S_];
#pragma unroll
    for (int s = 0; s < S_; ++s) {
        float q = supv[s] * supv[s];
        float r = supv[s] * tg;
#pragma unroll
        for (int off = 32; off; off >>= 1) {
            q += __shfl_xor(q, off);
            r += __shfl_xor(r, off);
        }
        sims[s] = r * rsqrtf(fmaxf(q, 1e-10f));
    }

    // softmax over S (redundant on all lanes)
    float mx = sims[0];
#pragma unroll
    for (int s = 1; s < S_; ++s) mx = fmaxf(mx, sims[s]);
    float se = 0.f;
#pragma unroll
    for (int s = 0; s < S_; ++s) { sims[s] = expf(sims[s] - mx); se += sims[s]; }
    const float inv = 1.f / se;

    // preds[c] on lanes c<20
    float pc = -INFINITY;
    if (d < C_) {
        pc = 0.f;
#pragma unroll
        for (int s = 0; s < S_; ++s)
            pc += sims[s] * inv * onehot[((size_t)b * S_ + s) * C_ + d];
    }

    // argmax with first-index tie-break (matches jnp.argmax)
    float v = pc;
    int idx = (d < C_) ? d : (1 << 30);
#pragma unroll
    for (int off = 32; off; off >>= 1) {
        const float ov = __shfl_xor(v, off);
        const int   oi = __shfl_xor(idx, off);
        if (ov > v || (ov == v && oi < idx)) { v = ov; idx = oi; }
    }
    // log-sum-exp of preds (max is v)
    float e = (d < C_) ? expf(pc - v) : 0.f;
#pragma unroll
    for (int off = 32; off; off >>= 1) e += __shfl_xor(e, off);
    const float lse = v + logf(e);

    const int ty = ty_[b];
    const float pty = __shfl(pc, ty);

    if (d == 0) {
        res[b]        = (idx == ty) ? 1.f : 0.f;
        res[B_ + b]   = lse - pty;     // -log_softmax(preds)[ty]
    }
}

// ---------------------------------------------------------------------------
// Phase 3: reduce 256 per-sample results -> [accuracy, loss] as FLOAT32.
// (Round-1 forensics: reference outputs are fp32 scalars; d_out is float*.)
// ---------------------------------------------------------------------------
__global__ __launch_bounds__(64)
void phase3_kernel(const float* __restrict__ res, float* __restrict__ out) {
    const int t = threadIdx.x;
    float c = 0.f, l = 0.f;
#pragma unroll
    for (int i = 0; i < 4; ++i) {
        c += res[t + 64 * i];
        l += res[B_ + t + 64 * i];
    }
#pragma unroll
    for (int off = 32; off; off >>= 1) {
        c += __shfl_xor(c, off);
        l += __shfl_xor(l, off);
    }
    if (t == 0) {
        out[0] = c * (1.f / 256.f);   // accuracy
        out[1] = l * (1.f / 256.f);   // crossentropy_loss
    }
}

extern "C" void kernel_launch(void* const* d_in, const int* in_sizes, int n_in,
                              void* d_out, int out_size, void* d_ws, size_t ws_size,
                              hipStream_t stream) {
    const float* sup    = (const float*)d_in[0];  // [256,20,20000]
    const float* onehot = (const float*)d_in[1];  // [256,20,20]
    const float* tgtim  = (const float*)d_in[2];  // [256,20000]
    const int*   ty     = (const int*)  d_in[3];  // [256]
    const float* W      = (const float*)d_in[4];  // [64,20000]
    const float* bias   = (const float*)d_in[5];  // [64]

    float* Ep  = (float*)d_ws;                               // [10][5376][64]
    float* res = Ep + (size_t)KSPLIT * MTOT * D_;            // [2][256]
    float* out = (float*)d_out;                              // [accuracy, loss] fp32

    gemm_part_kernel<<<dim3(MTOT / MT, KSPLIT), 256, 0, stream>>>(sup, tgtim, W, Ep);
    phase2_kernel<<<B_, 64, 0, stream>>>(Ep, bias, onehot, ty, res);
    phase3_kernel<<<1, 64, 0, stream>>>(res, out);
}

// Round 3
// 742.533 us; speedup vs baseline: 1.1014x; 1.1014x over previous
//
#include <hip/hip_runtime.h>
#include <hip/hip_bf16.h>
#include <math.h>

// Problem constants
#define B_  256
#define S_  20
#define V_  20000
#define C_  20
#define D_  64
#define MTOT (B_*S_ + B_)      // 5376 rows: 5120 support + 256 target
#define KSPLIT 10
#define KCHUNK (V_/KSPLIT)     // 2000
#define KC 80                  // real k staged per chunk
#define LROW 104               // LDS row stride in bf16 units: 96 mfma-k + 8 pad
#define MT 64

typedef __bf16 bf16x8 __attribute__((ext_vector_type(8)));
typedef float  f32x4  __attribute__((ext_vector_type(4)));

// Split float4 into truncated-bf16 hi + bf16(residual) lo, packed as 2 dwords each.
// x = hi + r exactly (Sterbenz); lo = trunc16(r): dropped lo*lo MFMA term ~2^-16 rel.
__device__ __forceinline__ void stage_store(unsigned short* hi, unsigned short* lo,
                                            float4 v) {
    unsigned int ux = __float_as_uint(v.x), uy = __float_as_uint(v.y),
                 uz = __float_as_uint(v.z), uw = __float_as_uint(v.w);
    unsigned int hx = ux & 0xFFFF0000u, hy = uy & 0xFFFF0000u,
                 hz = uz & 0xFFFF0000u, hw = uw & 0xFFFF0000u;
    uint2 h; h.x = (hx >> 16) | hy; h.y = (hz >> 16) | hw;
    *(uint2*)hi = h;
    float rx = v.x - __uint_as_float(hx), ry = v.y - __uint_as_float(hy),
          rz = v.z - __uint_as_float(hz), rw = v.w - __uint_as_float(hw);
    uint2 l;
    l.x = (__float_as_uint(rx) >> 16) | (__float_as_uint(ry) & 0xFFFF0000u);
    l.y = (__float_as_uint(rz) >> 16) | (__float_as_uint(rw) & 0xFFFF0000u);
    *(uint2*)lo = l;
}

// ---------------------------------------------------------------------------
// Phase 1: Ep[bk][m][d] = sum_{k in chunk bk} X[m][k]*W[d][k]  via bf16 MFMA.
// Block: 64 rows x 64 cols, 4 waves; wave w owns m-strip [16w,16w+16), 4 n-tiles.
// ---------------------------------------------------------------------------
__global__ __launch_bounds__(256)
void gemm_mfma_kernel(const float* __restrict__ sup,
                      const float* __restrict__ tgtim,
                      const float* __restrict__ W,
                      float* __restrict__ Ep) {
    __shared__ unsigned short Xhi[MT * LROW], Xlo[MT * LROW];
    __shared__ unsigned short Whi[D_ * LROW], Wlo[D_ * LROW];

    const int bm = blockIdx.x;          // 0..83
    const int bk = blockIdx.y;          // 0..9
    const int t  = threadIdx.x;
    const int w    = t >> 6;            // wave 0..3
    const int lane = t & 63;
    const int ln = lane & 15;           // fragment row/col
    const int qd = lane >> 4;           // quad 0..3
    const int m0 = bm * MT;

    const float* xbase = (m0 < B_*S_)
        ? (sup   + (size_t)m0 * V_)
        : (tgtim + (size_t)(m0 - B_*S_) * V_);

    // Zero the k=80..95 pad once (3rd MFMA k-step reads it; never re-written).
    for (int u = t; u < 4 * 64 * 8; u += 256) {       // 4 arrays x 64 rows x 8 dwords
        const int arr = u >> 9, rem = u & 511;
        const int r = rem >> 3, c = rem & 7;
        unsigned short* base = (arr == 0) ? Xhi : (arr == 1) ? Xlo
                             : (arr == 2) ? Whi : Wlo;
        *(unsigned int*)&base[r * LROW + KC + c * 2] = 0u;
    }

    f32x4 acc[4];
#pragma unroll
    for (int i = 0; i < 4; ++i) acc[i] = (f32x4){0.f, 0.f, 0.f, 0.f};

    const size_t kbase0 = (size_t)bk * KCHUNK;

    for (int ch = 0; ch < KCHUNK / KC; ++ch) {        // 25 chunks
        const size_t kb = kbase0 + (size_t)ch * KC;
        __syncthreads();
        // Stage X tile: 64 rows x 20 float4 (5 per thread), split hi/lo.
        {
            int u = t;
#pragma unroll
            for (int it = 0; it < 5; ++it, u += 256) {
                const int r = u / 20, c = u % 20;
                const float4 v = *(const float4*)(xbase + (size_t)r * V_ + kb + c * 4);
                stage_store(&Xhi[r * LROW + c * 4], &Xlo[r * LROW + c * 4], v);
            }
            u = t;
#pragma unroll
            for (int it = 0; it < 5; ++it, u += 256) {
                const int r = u / 20, c = u % 20;
                const float4 v = *(const float4*)(W + (size_t)r * V_ + kb + c * 4);
                stage_store(&Whi[r * LROW + c * 4], &Wlo[r * LROW + c * 4], v);
            }
        }
        __syncthreads();

#pragma unroll
        for (int ks = 0; ks < 3; ++ks) {              // K=96 (last 16 are zeros)
            const int k0 = ks * 32 + qd * 8;
            const bf16x8 ah = *(const bf16x8*)&Xhi[(16 * w + ln) * LROW + k0];
            const bf16x8 al = *(const bf16x8*)&Xlo[(16 * w + ln) * LROW + k0];
#pragma unroll
            for (int tt = 0; tt < 4; ++tt) {
                const bf16x8 bh = *(const bf16x8*)&Whi[(16 * tt + ln) * LROW + k0];
                const bf16x8 bl = *(const bf16x8*)&Wlo[(16 * tt + ln) * LROW + k0];
                acc[tt] = __builtin_amdgcn_mfma_f32_16x16x32_bf16(ah, bh, acc[tt], 0, 0, 0);
                acc[tt] = __builtin_amdgcn_mfma_f32_16x16x32_bf16(ah, bl, acc[tt], 0, 0, 0);
                acc[tt] = __builtin_amdgcn_mfma_f32_16x16x32_bf16(al, bh, acc[tt], 0, 0, 0);
            }
        }
    }

    // Epilogue: C/D layout col=lane&15, row=(lane>>4)*4+reg (m89/m91-verified).
    const size_t mrow = (size_t)m0 + 16 * w + qd * 4;
#pragma unroll
    for (int tt = 0; tt < 4; ++tt)
#pragma unroll
        for (int r = 0; r < 4; ++r)
            Ep[((size_t)bk * MTOT + mrow + r) * D_ + 16 * tt + ln] = acc[tt][r];
}

// ---------------------------------------------------------------------------
// Phase 2a: in-place K-split reduction: Ep[0][i] = sum_p Ep[p][i] (float4-wide).
// ---------------------------------------------------------------------------
__global__ __launch_bounds__(256)
void reduce_kernel(float* __restrict__ Ep) {
    const size_t i = (size_t)blockIdx.x * 256 + threadIdx.x;  // over 86016 float4
    const size_t stride = (size_t)MTOT * D_;                  // 344064 floats
    float4 s = *(const float4*)(Ep + i * 4);
#pragma unroll
    for (int p = 1; p < KSPLIT; ++p) {
        const float4 v = *(const float4*)(Ep + p * stride + i * 4);
        s.x += v.x; s.y += v.y; s.z += v.z; s.w += v.w;
    }
    *(float4*)(Ep + i * 4) = s;
}

// ---------------------------------------------------------------------------
// Phase 2b: per-sample distance + softmax + preds + argmax + CE (verified R2).
// ---------------------------------------------------------------------------
__global__ __launch_bounds__(64)
void phase2_kernel(const float* __restrict__ E0,
                   const float* __restrict__ bias,
                   const float* __restrict__ onehot,
                   const int*   __restrict__ ty_,
                   float* __restrict__ res) {
    const int b = blockIdx.x;
    const int d = threadIdx.x;
    const float bv = bias[d];

    float supv[S_];
#pragma unroll
    for (int s = 0; s < S_; ++s)
        supv[s] = E0[((size_t)b * S_ + s) * D_ + d] + bv;
    float tg = E0[((size_t)(B_ * S_) + b) * D_ + d] + bv;

    float sims[S_];
#pragma unroll
    for (int s = 0; s < S_; ++s) {
        float q = supv[s] * supv[s];
        float r = supv[s] * tg;
#pragma unroll
        for (int off = 32; off; off >>= 1) {
            q += __shfl_xor(q, off);
            r += __shfl_xor(r, off);
        }
        sims[s] = r * rsqrtf(fmaxf(q, 1e-10f));
    }

    float mx = sims[0];
#pragma unroll
    for (int s = 1; s < S_; ++s) mx = fmaxf(mx, sims[s]);
    float se = 0.f;
#pragma unroll
    for (int s = 0; s < S_; ++s) { sims[s] = expf(sims[s] - mx); se += sims[s]; }
    const float inv = 1.f / se;

    float pc = -INFINITY;
    if (d < C_) {
        pc = 0.f;
#pragma unroll
        for (int s = 0; s < S_; ++s)
            pc += sims[s] * inv * onehot[((size_t)b * S_ + s) * C_ + d];
    }

    float v = pc;
    int idx = (d < C_) ? d : (1 << 30);
#pragma unroll
    for (int off = 32; off; off >>= 1) {
        const float ov = __shfl_xor(v, off);
        const int   oi = __shfl_xor(idx, off);
        if (ov > v || (ov == v && oi < idx)) { v = ov; idx = oi; }
    }
    float e = (d < C_) ? expf(pc - v) : 0.f;
#pragma unroll
    for (int off = 32; off; off >>= 1) e += __shfl_xor(e, off);
    const float lse = v + logf(e);

    const int ty = ty_[b];
    const float pty = __shfl(pc, ty);

    if (d == 0) {
        res[b]      = (idx == ty) ? 1.f : 0.f;
        res[B_ + b] = lse - pty;
    }
}

// ---------------------------------------------------------------------------
// Phase 3: reduce 256 per-sample results -> [accuracy, loss] fp32.
// ---------------------------------------------------------------------------
__global__ __launch_bounds__(64)
void phase3_kernel(const float* __restrict__ res, float* __restrict__ out) {
    const int t = threadIdx.x;
    float c = 0.f, l = 0.f;
#pragma unroll
    for (int i = 0; i < 4; ++i) {
        c += res[t + 64 * i];
        l += res[B_ + t + 64 * i];
    }
#pragma unroll
    for (int off = 32; off; off >>= 1) {
        c += __shfl_xor(c, off);
        l += __shfl_xor(l, off);
    }
    if (t == 0) {
        out[0] = c * (1.f / 256.f);
        out[1] = l * (1.f / 256.f);
    }
}

extern "C" void kernel_launch(void* const* d_in, const int* in_sizes, int n_in,
                              void* d_out, int out_size, void* d_ws, size_t ws_size,
                              hipStream_t stream) {
    const float* sup    = (const float*)d_in[0];
    const float* onehot = (const float*)d_in[1];
    const float* tgtim  = (const float*)d_in[2];
    const int*   ty     = (const int*)  d_in[3];
    const float* W      = (const float*)d_in[4];
    const float* bias   = (const float*)d_in[5];

    float* Ep  = (float*)d_ws;                        // [10][5376][64]
    float* res = Ep + (size_t)KSPLIT * MTOT * D_;     // [2][256]
    float* out = (float*)d_out;

    gemm_mfma_kernel<<<dim3(MTOT / MT, KSPLIT), 256, 0, stream>>>(sup, tgtim, W, Ep);
    reduce_kernel<<<(MTOT * D_ / 4) / 256, 256, 0, stream>>>(Ep);
    phase2_kernel<<<B_, 64, 0, stream>>>(Ep, bias, onehot, ty, res);
    phase3_kernel<<<1, 64, 0, stream>>>(res, out);
}

// Round 4
// 666.755 us; speedup vs baseline: 1.2265x; 1.1137x over previous
//
#include <hip/hip_runtime.h>
#include <hip/hip_bf16.h>
#include <math.h>

// Problem constants
#define B_  256
#define S_  20
#define V_  20000
#define C_  20
#define D_  64
#define MTOT (B_*S_ + B_)      // 5376 rows: 5120 support + 256 target
#define KSPLIT 10
#define NK32 625               // 20000 / 32 fp32-K units

typedef __bf16 bf16x8 __attribute__((ext_vector_type(8)));
typedef float  f32x4  __attribute__((ext_vector_type(4)));

// Split 8 fp32 into truncated-bf16 hi (uint4) + bf16(residual) lo (uint4).
// x = hi + r exactly; dropped lo*lo MFMA term ~2^-16 rel (R3: absmax 0.0).
__device__ __forceinline__ void split8(const float4 a, const float4 b,
                                       uint4& hi, uint4& lo) {
    const float f[8] = {a.x, a.y, a.z, a.w, b.x, b.y, b.z, b.w};
    unsigned int h[8]; float r[8];
#pragma unroll
    for (int j = 0; j < 8; ++j) {
        const unsigned int u = __float_as_uint(f[j]);
        h[j] = u & 0xFFFF0000u;
        r[j] = f[j] - __uint_as_float(h[j]);
    }
    hi.x = (h[0] >> 16) | h[1];
    hi.y = (h[2] >> 16) | h[3];
    hi.z = (h[4] >> 16) | h[5];
    hi.w = (h[6] >> 16) | h[7];
    lo.x = (__float_as_uint(r[0]) >> 16) | (__float_as_uint(r[1]) & 0xFFFF0000u);
    lo.y = (__float_as_uint(r[2]) >> 16) | (__float_as_uint(r[3]) & 0xFFFF0000u);
    lo.z = (__float_as_uint(r[4]) >> 16) | (__float_as_uint(r[5]) & 0xFFFF0000u);
    lo.w = (__float_as_uint(r[6]) >> 16) | (__float_as_uint(r[7]) & 0xFFFF0000u);
}

// ---------------------------------------------------------------------------
// wconv: W [64][20000] fp32 -> B-fragment-ordered bf16 hi/lo arrays.
// Layout: Wf[(c*4 + tt)*64 + lane] (uint4); lane holds W[16tt+(lane&15)]
// [c*32 + (lane>>4)*8 + j], j=0..7 — exactly the mfma_16x16x32_bf16 B frag.
// ---------------------------------------------------------------------------
__global__ __launch_bounds__(256)
void wconv_kernel(const float* __restrict__ W,
                  uint4* __restrict__ Wfh, uint4* __restrict__ Wfl) {
    const int g    = blockIdx.x * 256 + threadIdx.x;   // 0..159999
    const int lane = g & 63;
    const int tt   = (g >> 6) & 3;
    const int c    = g >> 8;
    const int ln = lane & 15, qd = lane >> 4;
    const float* src = W + (size_t)(16 * tt + ln) * V_ + c * 32 + qd * 8;
    const float4 a = *(const float4*)src;
    const float4 b = *(const float4*)(src + 4);
    uint4 h, l; split8(a, b, h, l);
    Wfh[g] = h; Wfl[g] = l;
}

// ---------------------------------------------------------------------------
// gemm2: barrier-free, LDS-free. Block = 4 independent waves; wave owns 16
// M-rows and a K-range. Per k32: A frag loaded global->reg->hi/lo split,
// B frags loaded pre-converted. 12 MFMAs. 1-ahead ping-pong prefetch.
// ---------------------------------------------------------------------------
__device__ __forceinline__ void ldx(const float* xrow, int c, float4& r0, float4& r1) {
    const float* p = xrow + (size_t)c * 32;
    r0 = *(const float4*)p;
    r1 = *(const float4*)(p + 4);
}
__device__ __forceinline__ void ldw(const uint4* bh, const uint4* bl, int c,
                                    uint4* wh, uint4* wl) {
    const uint4* ph = bh + (size_t)c * 256;
    const uint4* pl = bl + (size_t)c * 256;
#pragma unroll
    for (int tt = 0; tt < 4; ++tt) { wh[tt] = ph[tt * 64]; wl[tt] = pl[tt * 64]; }
}
__device__ __forceinline__ void step(const float4 x0, const float4 x1,
                                     const uint4* wh, const uint4* wl, f32x4* acc) {
    uint4 hu, lu; split8(x0, x1, hu, lu);
    const bf16x8 ah = *(const bf16x8*)&hu;
    const bf16x8 al = *(const bf16x8*)&lu;
#pragma unroll
    for (int tt = 0; tt < 4; ++tt) {
        const bf16x8 bh = *(const bf16x8*)&wh[tt];
        const bf16x8 bl = *(const bf16x8*)&wl[tt];
        acc[tt] = __builtin_amdgcn_mfma_f32_16x16x32_bf16(ah, bh, acc[tt], 0, 0, 0);
        acc[tt] = __builtin_amdgcn_mfma_f32_16x16x32_bf16(ah, bl, acc[tt], 0, 0, 0);
        acc[tt] = __builtin_amdgcn_mfma_f32_16x16x32_bf16(al, bh, acc[tt], 0, 0, 0);
    }
}

__global__ __launch_bounds__(256)
void gemm2_kernel(const float* __restrict__ sup,
                  const float* __restrict__ tgtim,
                  const uint4* __restrict__ Wfh,
                  const uint4* __restrict__ Wfl,
                  float* __restrict__ Ep) {
    const int bmx = blockIdx.x;         // 0..83 (M-block of 64 rows)
    const int bk  = blockIdx.y;         // 0..9  (K-split)
    const int t = threadIdx.x;
    const int w = t >> 6, lane = t & 63;
    const int ln = lane & 15, qd = lane >> 4;
    const int m0 = bmx * 64;

    const float* xbase = (m0 < B_*S_)
        ? (sup   + (size_t)m0 * V_)
        : (tgtim + (size_t)(m0 - B_*S_) * V_);
    const float* xrow = xbase + (size_t)(16 * w + ln) * V_ + qd * 8;
    const uint4* wbh = Wfh + lane;
    const uint4* wbl = Wfl + lane;

    // ragged K-split: 625 = 5*63 + 5*62
    const int nk = (bk < 5) ? 63 : 62;
    const int c0 = bk * 62 + ((bk < 5) ? bk : 5);

    f32x4 acc[4];
#pragma unroll
    for (int i = 0; i < 4; ++i) acc[i] = (f32x4){0.f, 0.f, 0.f, 0.f};

    float4 xa0, xa1, xc0, xc1;
    uint4 wha[4], wla[4], whb[4], wlb[4];

    ldx(xrow, c0, xa0, xa1);
    ldw(wbh, wbl, c0, wha, wla);

    int i = 0;
    for (; i + 2 <= nk; i += 2) {
        const int c1 = c0 + i + 1;
        ldx(xrow, c1, xc0, xc1);
        ldw(wbh, wbl, c1, whb, wlb);
        step(xa0, xa1, wha, wla, acc);
        const int c2 = c0 + ((i + 2 < nk) ? (i + 2) : (i + 1));  // clamp: dummy reload
        ldx(xrow, c2, xa0, xa1);
        ldw(wbh, wbl, c2, wha, wla);
        step(xc0, xc1, whb, wlb, acc);
    }
    if (i < nk) step(xa0, xa1, wha, wla, acc);   // nk odd tail

    // C/D layout (m89/m91): col(lane&15)=n, row((lane>>4)*4+reg)=m
    float* dst = Ep + ((size_t)bk * MTOT + m0 + 16 * w + qd * 4) * D_ + ln;
#pragma unroll
    for (int tt = 0; tt < 4; ++tt)
#pragma unroll
        for (int r = 0; r < 4; ++r)
            dst[(size_t)r * D_ + 16 * tt] = acc[tt][r];
}

// ---------------------------------------------------------------------------
// Phase 2a: in-place K-split reduction: Ep[0][i] = sum_p Ep[p][i].
// ---------------------------------------------------------------------------
__global__ __launch_bounds__(256)
void reduce_kernel(float* __restrict__ Ep) {
    const size_t i = (size_t)blockIdx.x * 256 + threadIdx.x;  // over 86016 float4
    const size_t stride = (size_t)MTOT * D_;
    float4 s = *(const float4*)(Ep + i * 4);
#pragma unroll
    for (int p = 1; p < KSPLIT; ++p) {
        const float4 v = *(const float4*)(Ep + p * stride + i * 4);
        s.x += v.x; s.y += v.y; s.z += v.z; s.w += v.w;
    }
    *(float4*)(Ep + i * 4) = s;
}

// ---------------------------------------------------------------------------
// Phase 2b: distance + softmax + preds + argmax + CE (verified R2/R3).
// ---------------------------------------------------------------------------
__global__ __launch_bounds__(64)
void phase2_kernel(const float* __restrict__ E0,
                   const float* __restrict__ bias,
                   const float* __restrict__ onehot,
                   const int*   __restrict__ ty_,
                   float* __restrict__ res) {
    const int b = blockIdx.x;
    const int d = threadIdx.x;
    const float bv = bias[d];

    float supv[S_];
#pragma unroll
    for (int s = 0; s < S_; ++s)
        supv[s] = E0[((size_t)b * S_ + s) * D_ + d] + bv;
    float tg = E0[((size_t)(B_ * S_) + b) * D_ + d] + bv;

    float sims[S_];
#pragma unroll
    for (int s = 0; s < S_; ++s) {
        float q = supv[s] * supv[s];
        float r = supv[s] * tg;
#pragma unroll
        for (int off = 32; off; off >>= 1) {
            q += __shfl_xor(q, off);
            r += __shfl_xor(r, off);
        }
        sims[s] = r * rsqrtf(fmaxf(q, 1e-10f));
    }

    float mx = sims[0];
#pragma unroll
    for (int s = 1; s < S_; ++s) mx = fmaxf(mx, sims[s]);
    float se = 0.f;
#pragma unroll
    for (int s = 0; s < S_; ++s) { sims[s] = expf(sims[s] - mx); se += sims[s]; }
    const float inv = 1.f / se;

    float pc = -INFINITY;
    if (d < C_) {
        pc = 0.f;
#pragma unroll
        for (int s = 0; s < S_; ++s)
            pc += sims[s] * inv * onehot[((size_t)b * S_ + s) * C_ + d];
    }

    float v = pc;
    int idx = (d < C_) ? d : (1 << 30);
#pragma unroll
    for (int off = 32; off; off >>= 1) {
        const float ov = __shfl_xor(v, off);
        const int   oi = __shfl_xor(idx, off);
        if (ov > v || (ov == v && oi < idx)) { v = ov; idx = oi; }
    }
    float e = (d < C_) ? expf(pc - v) : 0.f;
#pragma unroll
    for (int off = 32; off; off >>= 1) e += __shfl_xor(e, off);
    const float lse = v + logf(e);

    const int ty = ty_[b];
    const float pty = __shfl(pc, ty);

    if (d == 0) {
        res[b]      = (idx == ty) ? 1.f : 0.f;
        res[B_ + b] = lse - pty;
    }
}

// ---------------------------------------------------------------------------
// Phase 3: reduce 256 per-sample results -> [accuracy, loss] fp32.
// ---------------------------------------------------------------------------
__global__ __launch_bounds__(64)
void phase3_kernel(const float* __restrict__ res, float* __restrict__ out) {
    const int t = threadIdx.x;
    float c = 0.f, l = 0.f;
#pragma unroll
    for (int i = 0; i < 4; ++i) {
        c += res[t + 64 * i];
        l += res[B_ + t + 64 * i];
    }
#pragma unroll
    for (int off = 32; off; off >>= 1) {
        c += __shfl_xor(c, off);
        l += __shfl_xor(l, off);
    }
    if (t == 0) {
        out[0] = c * (1.f / 256.f);
        out[1] = l * (1.f / 256.f);
    }
}

extern "C" void kernel_launch(void* const* d_in, const int* in_sizes, int n_in,
                              void* d_out, int out_size, void* d_ws, size_t ws_size,
                              hipStream_t stream) {
    const float* sup    = (const float*)d_in[0];
    const float* onehot = (const float*)d_in[1];
    const float* tgtim  = (const float*)d_in[2];
    const int*   ty     = (const int*)  d_in[3];
    const float* W      = (const float*)d_in[4];
    const float* bias   = (const float*)d_in[5];

    // ws layout: Ep [10][5376][64] f32 | res [2][256] f32 | Wfh | Wfl (2.56MB each)
    float* Ep  = (float*)d_ws;
    float* res = Ep + (size_t)KSPLIT * MTOT * D_;
    uint4* Wfh = (uint4*)(res + 512);
    uint4* Wfl = Wfh + (size_t)NK32 * 4 * 64;
    float* out = (float*)d_out;

    wconv_kernel<<<625, 256, 0, stream>>>(W, Wfh, Wfl);
    gemm2_kernel<<<dim3(84, KSPLIT), 256, 0, stream>>>(sup, tgtim, Wfh, Wfl, Ep);
    reduce_kernel<<<(MTOT * D_ / 4) / 256, 256, 0, stream>>>(Ep);
    phase2_kernel<<<B_, 64, 0, stream>>>(Ep, bias, onehot, ty, res);
    phase3_kernel<<<1, 64, 0, stream>>>(res, out);
}